// Round 7
// baseline (910.977 us; speedup 1.0000x reference)
//
#include <hip/hip_runtime.h>

// R23: chunk-level software pipelining across dispatches.
// Evidence: 7 structural variants tie at ~90us/trace-dispatch (MfmaUtil ~30%,
// no saturated pipe); intra-kernel scheduling is exhausted (8-phase transfer
// at K=1024 is only +10% per learn_hip m248). The untapped parallelism is
// INTER-dispatch: B2(chunk c) and B1(chunk c+1) are independent.
//  - Cores: revert to R16's proven 128^2 / 256-thread / 4-blocks-per-CU
//    bodies (best combined MFMA+VALU util of all variants).
//  - B1's B-operand built on the fly (w0 (*) d0, bitwise == old g0_body):
//    G0 (64MB write + ~4x read) deleted; at 4 blk/CU the TLP R21 lacked
//    covers the staging chain. Freed workspace -> double-buffered Upr.
//  - Pipeline: B1(c0); [B2(c0) u B1(c1)]; [B2(c1) u B1(c2)];
//    [B2(c2) u B1(c3)]; B2(c3). Fused grids interleave types in groups of 8
//    (sel = (bid>>3)&1, idx = ((bid>>4)<<3)|(bid&7)) -> both sub-grids keep
//    bid%8 XCD phase; every CU gets a mix of VALU-heavy B1 and HBM/MFMA-
//    heavy B2 blocks (m114 pipe overlap).
// Numerics: B1/B2 math identical to R16 (same MFMA order, same epilogues;
// OTF B uses g0_body's exact float-mul->bf16-round) -> Upr bitwise
// identical; tr regroups only its nondeterministic atomic order.
// absmax must stay 0.009765625.

typedef __bf16 bf16;
typedef __bf16 bf16x8 __attribute__((ext_vector_type(8)));
typedef float floatx4 __attribute__((ext_vector_type(4)));

#if defined(__has_builtin)
#if __has_builtin(__builtin_amdgcn_global_load_lds)
#define HAVE_GLL 1
#endif
#endif

typedef __attribute__((address_space(3))) char lds_char_t;
typedef __attribute__((address_space(1))) const char gbl_char_t;

__device__ inline void async_load16(const void* gp, void* lp) {
#ifdef HAVE_GLL
  __builtin_amdgcn_global_load_lds((gbl_char_t*)gp, (lds_char_t*)lp, 16, 0, 0);
#else
  *(bf16x8*)lp = *(const bf16x8*)gp;
#endif
}

// ---------------- shared 128^2 helpers ----------------
__device__ inline void stage_async(const bf16* src, long row0, int ld, int kc,
                                   bf16* dst, int wid, int sr8, int cph) {
#pragma unroll
  for (int t = 0; t < 4; ++t) {
    const int r = (wid * 4 + t) * 8 + sr8;
    const int csrc = (cph - r) & 7;
    async_load16(src + (row0 + r) * (size_t)ld + kc + csrc * 8,
                 dst + r * 64 + cph * 8);
  }
}

// On-the-fly B staging for B1: row r of the tile is gene-dim d=r of one
// sample; value = w0b[wsel][k] * d0[k], g0_body's exact formula/rounding.
__device__ inline void stage_b_otf(const bf16* w0b, const bf16* d0row, int kc,
                                   bf16* dst, int wid, int sr8, int cph) {
#pragma unroll
  for (int t = 0; t < 4; ++t) {
    const int r = (wid * 4 + t) * 8 + sr8;
    const int csrc = (cph - r) & 7;
    const int wsel = (r + 1 < 128) ? r + 1 : 127;   // d==127 pad (masked in B2)
    const int off = kc + csrc * 8;
    bf16x8 wv = *(const bf16x8*)(w0b + wsel * 1024 + off);
    bf16x8 dv = *(const bf16x8*)(d0row + off);
    bf16x8 o;
#pragma unroll
    for (int k = 0; k < 8; ++k) o[k] = (bf16)((float)wv[k] * (float)dv[k]);
    *(bf16x8*)(dst + r * 64 + cph * 8) = o;
  }
}

__device__ inline void mfma_block(const bf16* As, const bf16* Bs,
                                  floatx4 (&acc)[4][4], int wm, int wn,
                                  int l16, int quad) {
#pragma unroll
  for (int ks = 0; ks < 2; ++ks) {
    bf16x8 af[4], bfv[4];
#pragma unroll
    for (int mt = 0; mt < 4; ++mt) {
      const int r = wm * 64 + mt * 16 + l16;
      const int c = (ks * 4 + quad + r) & 7;
      af[mt] = *(const bf16x8*)(As + r * 64 + c * 8);
    }
#pragma unroll
    for (int nt = 0; nt < 4; ++nt) {
      const int r = wn * 64 + nt * 16 + l16;
      const int c = (ks * 4 + quad + r) & 7;
      bfv[nt] = *(const bf16x8*)(Bs + r * 64 + c * 8);
    }
#pragma unroll
    for (int mt = 0; mt < 4; ++mt)
#pragma unroll
      for (int nt = 0; nt < 4; ++nt)
        acc[mt][nt] = __builtin_amdgcn_mfma_f32_16x16x32_bf16(af[mt], bfv[nt], acc[mt][nt], 0, 0, 0);
  }
}

// ---------------- fused trace pipeline kernel ----------------
struct T12 {
  // B1 side (writes UprW for chunk i0b1)
  const bf16* A1;    // gw1t (ld 1024)
  const bf16* w0b;   // gw0b 128x1024
  const bf16* d0b;   // 1024x1024
  const bf16* d1b;   // 1024x960
  bf16* UprW;
  int i0b1;
  // B2 side (reads UprR for chunk i0b2)
  const bf16* A2;    // gw2t (ld 1024, zero-padded rows)
  const bf16* UprR;
  const bf16* d2b;   // 1024x896
  const float* gdw;  // 896x128 (f32)
  float* tr;
  int i0b2;
  int ch;            // chunk size (equal for both sides)
};

// B1: U' rows = d1 * (gw1^T @ [w0 (*) d0]-rows)  -- R16 body + OTF B.
__device__ inline void b1_body(const T12& p, int idx, char* ldsRaw) {
  const int mt8 = (idx >> 3) & 7;
  const int nb  = ((idx >> 6) << 3) + (idx & 7);
  if (nb >= p.ch) return;

  bf16* As = (bf16*)ldsRaw;
  bf16* Bs = As + 8192;
  bf16* bounce = (bf16*)ldsRaw;

  const int tid  = threadIdx.x;
  const int wid  = tid >> 6, lane = tid & 63;
  const int wm   = wid & 1, wn = wid >> 1;
  const int quad = lane >> 4, l16 = lane & 15;
  const int sr8  = lane >> 3, cph = lane & 7;
  const int m0   = mt8 * 128;
  const int ig   = p.i0b1 + nb;
  const int n0   = nb * 128;
  const bf16* d0row = p.d0b + (size_t)ig * 1024;

  floatx4 acc[4][4];
#pragma unroll
  for (int a = 0; a < 4; ++a)
#pragma unroll
    for (int b = 0; b < 4; ++b)
#pragma unroll
      for (int r = 0; r < 4; ++r) acc[a][b][r] = 0.0f;

  for (int kc = 0; kc < 1024; kc += 64) {
    stage_async(p.A1, m0, 1024, kc, As, wid, sr8, cph);
    stage_b_otf(p.w0b, d0row, kc, Bs, wid, sr8, cph);
    __syncthreads();
    mfma_block(As, Bs, acc, wm, wn, l16, quad);
    __syncthreads();
  }

#pragma unroll
  for (int nt = 0; nt < 4; ++nt) {
    const int nl = wn * 64 + nt * 16 + l16;
#pragma unroll
    for (int mt = 0; mt < 4; ++mt)
#pragma unroll
      for (int r = 0; r < 4; ++r) {
        const int ml = wm * 64 + mt * 16 + quad * 4 + r;
        const int mg = m0 + ml;
        const float d1v = (mg < 960) ? (float)p.d1b[(size_t)ig * 960 + mg] : 0.0f;
        bounce[nl * 136 + ml] = (bf16)(acc[mt][nt][r] * d1v);
      }
  }
  __syncthreads();
  const int r2 = tid >> 1, half16 = tid & 1;
  const int chLim = (mt8 == 7) ? 8 : 16;   // cols >=960 never read (B2 K=960)
#pragma unroll
  for (int c = 0; c < 8; ++c) {
    const int ch16 = half16 * 8 + c;
    if (ch16 < chLim) {
      bf16x8 v = *(const bf16x8*)(bounce + r2 * 136 + ch16 * 8);
      *(bf16x8*)(p.UprW + (size_t)(n0 + r2) * 1024 + m0 + ch16 * 8) = v;
    }
  }
}

// B2: tr[ig] += sum_d ((gw2t @ Upr) * d2 * gdw[:,d])  -- R16 body.
__device__ inline void b2_body(const T12& p, int idx, char* ldsRaw,
                               float* red4) {
  const int mt8 = (idx >> 3) & 7;
  const int nb  = ((idx >> 6) << 3) + (idx & 7);
  if (nb >= p.ch || mt8 == 7) return;      // B2 has 7 m-tiles (M=896)

  bf16* As = (bf16*)ldsRaw;
  bf16* Bs = As + 8192;

  const int tid  = threadIdx.x;
  const int wid  = tid >> 6, lane = tid & 63;
  const int wm   = wid & 1, wn = wid >> 1;
  const int quad = lane >> 4, l16 = lane & 15;
  const int sr8  = lane >> 3, cph = lane & 7;
  const int m0   = mt8 * 128;
  const int ig   = p.i0b2 + nb;
  const int n0   = nb * 128;

  floatx4 acc[4][4];
#pragma unroll
  for (int a = 0; a < 4; ++a)
#pragma unroll
    for (int b = 0; b < 4; ++b)
#pragma unroll
      for (int r = 0; r < 4; ++r) acc[a][b][r] = 0.0f;

  for (int kc = 0; kc < 960; kc += 64) {
    stage_async(p.A2, m0, 1024, kc, As, wid, sr8, cph);
    stage_async(p.UprR, n0, 1024, kc, Bs, wid, sr8, cph);
    __syncthreads();
    mfma_block(As, Bs, acc, wm, wn, l16, quad);
    __syncthreads();
  }

  float s = 0.0f;
#pragma unroll
  for (int nt = 0; nt < 4; ++nt) {
    const int d = wn * 64 + nt * 16 + l16;
    if (d < 127) {
#pragma unroll
      for (int mt = 0; mt < 4; ++mt)
#pragma unroll
        for (int r = 0; r < 4; ++r) {
          const int mg = m0 + wm * 64 + mt * 16 + quad * 4 + r;  // < 896
          const float w = (float)p.d2b[(size_t)ig * 896 + mg] * p.gdw[mg * 128 + d];
          s += acc[mt][nt][r] * w;
        }
    }
  }
#pragma unroll
  for (int off = 1; off < 64; off <<= 1) s += __shfl_xor(s, off, 64);
  if (lane == 0) red4[wid] = s;
  __syncthreads();
  if (tid == 0) atomicAdd(p.tr + ig, red4[0] + red4[1] + red4[2] + red4[3]);
}

// Fused dispatch: blocks [0,nB2) run B2(chunk i0b2), blocks [nB2,nB2+nB1)
// run B1(chunk i0b1); interleaved in groups of 8 to preserve XCD phase and
// mix block types on every CU.
__global__ __launch_bounds__(256, 4) void kt_b12(T12 p, int nB2, int nB1) {
  __shared__ __align__(16) char lds[34816];
  __shared__ float red4[4];
  const int bid = blockIdx.x;
  int sel, idx;
  if (nB2 > 0 && nB1 > 0) {
    sel = (bid >> 3) & 1;
    idx = ((bid >> 4) << 3) | (bid & 7);
  } else {
    sel = (nB2 > 0) ? 0 : 1;
    idx = bid;
  }
  if (sel == 0) b2_body(p, idx, lds, red4);
  else          b1_body(p, idx, lds);
}

// ---------------- forward GEMMs (unchanged core) ----------------
struct FArgs {
  const bf16* A; int lda;
  const bf16* Bt; int ldb;
  const float* bias;
  bf16* C; int ldc;
  bf16* D; int ldd;
  float* outF; int ldo;
  int K; int realN; int gridX;
};

template <int ACT>
__device__ inline void fwd_body(const FArgs& p, int bx, bf16* As, bf16* Bs) {
  const int tid  = threadIdx.x;
  const int wid  = tid >> 6, lane = tid & 63;
  const int wm   = wid & 1, wn = wid >> 1;
  const int quad = lane >> 4, l16 = lane & 15;
  const int sr8  = lane >> 3, cph = lane & 7;
  const int m0   = (bx % p.gridX) * 128;
  const int bn0  = (bx / p.gridX) * 128;

  floatx4 acc[4][4];
#pragma unroll
  for (int a = 0; a < 4; ++a)
#pragma unroll
    for (int b = 0; b < 4; ++b)
#pragma unroll
      for (int r = 0; r < 4; ++r) acc[a][b][r] = 0.0f;

  for (int kc = 0; kc < p.K; kc += 64) {
    stage_async(p.A, m0, p.lda, kc, As, wid, sr8, cph);
    stage_async(p.Bt, bn0, p.ldb, kc, Bs, wid, sr8, cph);
    __syncthreads();
    mfma_block(As, Bs, acc, wm, wn, l16, quad);
    __syncthreads();
  }

#pragma unroll
  for (int nt = 0; nt < 4; ++nt) {
    const int ng = bn0 + wn * 64 + nt * 16 + l16;
    const float bv = (ng < p.realN) ? p.bias[ng] : 0.0f;
#pragma unroll
    for (int mt = 0; mt < 4; ++mt)
#pragma unroll
      for (int r = 0; r < 4; ++r) {
        const int i = m0 + wm * 64 + mt * 16 + quad * 4 + r;
        const float v = acc[mt][nt][r] + bv;
        if (ACT) {
          const float t = tanhf(v);
          p.C[(size_t)i * p.ldc + ng] = (ng < p.realN) ? (bf16)t : (bf16)0.0f;
          if (p.D && ng < p.realN)
            p.D[(size_t)i * p.ldd + ng] = (bf16)(1.0f - t * t);
        } else if (ng < p.realN) {
          p.outF[(size_t)i * p.ldo + ng] = v;
        }
      }
  }
}

__global__ __launch_bounds__(256) void kt_fwd2(FArgs a, int na, FArgs b) {
  __shared__ __align__(16) bf16 As[8192];
  __shared__ __align__(16) bf16 Bs[8192];
  const int bx = blockIdx.x;
  if (bx < na) fwd_body<1>(a, bx, As, Bs);
  else         fwd_body<1>(b, bx - na, As, Bs);
}

__global__ __launch_bounds__(256) void kt_fwd1(FArgs a) {
  __shared__ __align__(16) bf16 As[8192];
  __shared__ __align__(16) bf16 Bs[8192];
  fwd_body<1>(a, blockIdx.x, As, Bs);
}

__global__ __launch_bounds__(256) void kt_dxgdot(FArgs a, int na,
                                                 const bf16* e1b, const float* bdw,
                                                 const float* bdb, float* gf,
                                                 float* gout) {
  __shared__ __align__(16) bf16 As[8192];
  __shared__ __align__(16) bf16 Bs[8192];
  const int bx = blockIdx.x;
  if (bx < na) { fwd_body<0>(a, bx, As, Bs); return; }
  const int i = (bx - na) * 4 + (threadIdx.x >> 6);
  const int lane = threadIdx.x & 63;
  float s = 0.0f;
  for (int k = lane; k < 448; k += 64) s += (float)e1b[(size_t)i * 512 + k] * bdw[k];
#pragma unroll
  for (int off = 32; off > 0; off >>= 1) s += __shfl_down(s, off, 64);
  if (lane == 0) {
    const float v = s + bdb[0];
    gf[i] = v;
    gout[i] = v;
  }
}

// ---------------- fused prep with LDS-tiled transposes ----------------
struct PArgs {
  const float *gw0, *gw1, *gw2, *gdw, *bw0, *bw1, *pt, *x;
  bf16 *gw0b, *gw0t, *gw1t, *gw2t, *gdwt, *bw0t, *bw1t, *Xg, *Xb;
};

__device__ inline void tpose_tile(bf16* dst, const float* src, int R, int C,
                                  int ldd, int tile, int tilesX, float* tl,
                                  int tid) {
  const int r0 = (tile % tilesX) * 64;
  const int c0 = (tile / tilesX) * 64;
  const int tx = tid & 63, ty0 = tid >> 6;
#pragma unroll
  for (int i = 0; i < 16; ++i) {
    const int ty = ty0 + i * 4;
    const int r = r0 + ty, c = c0 + tx;
    tl[ty * 65 + tx] = (r < R && c < C) ? src[(size_t)r * C + c] : 0.0f;
  }
  __syncthreads();
#pragma unroll
  for (int i = 0; i < 16; ++i) {
    const int ty = ty0 + i * 4;
    dst[(size_t)(c0 + ty) * ldd + r0 + tx] = (bf16)tl[tx * 65 + ty];
  }
}

__global__ __launch_bounds__(256) void kt_prep(PArgs p) {
  __shared__ float tl[64 * 65];
  int b = blockIdx.x;
  const int t = threadIdx.x;
  if (b < 512) { p.gw0b[b * 256 + t] = (bf16)p.gw0[b * 256 + t]; return; }
  b -= 512;
  if (b < 768) {  // build Xg/Xb
    const int idx = b * 256 + t;
    const int i = idx / 192, c = idx % 192;
    const float s = p.pt[0];
    float vb;
    if (c == 0) vb = s;
    else if (c <= 128) vb = p.x[i * 128 + c - 1];
    else vb = 0.0f;
    p.Xb[i * 192 + c] = (bf16)vb;
    if (c < 128) p.Xg[i * 128 + c] = (bf16)((c == 0) ? s : p.x[i * 128 + c - 1]);
    return;
  }
  b -= 768;
  if (b < 32)  { tpose_tile(p.gw0t, p.gw0, 128, 1024, 128, b, 2, tl, t);  return; }
  b -= 32;
  if (b < 256) { tpose_tile(p.gw1t, p.gw1, 1024, 960, 1024, b, 16, tl, t); return; }
  b -= 256;
  if (b < 256) { tpose_tile(p.gw2t, p.gw2, 960, 896, 1024, b, 16, tl, t); return; }
  b -= 256;
  if (b < 32)  { tpose_tile(p.gdwt, p.gdw, 896, 128, 1024, b, 16, tl, t); return; }
  b -= 32;
  if (b < 24)  { tpose_tile(p.bw0t, p.bw0, 129, 512, 192, b, 3, tl, t);  return; }
  b -= 24;
  if (b < 64)  { tpose_tile(p.bw1t, p.bw1, 512, 448, 512, b, 8, tl, t);  return; }
}

__global__ __launch_bounds__(256) void kt_fin(const float* gf, const float* tr,
                                              const float* pp, float* dp) {
  const int i = blockIdx.x * 256 + threadIdx.x;
  if (i < 1024) dp[i] = gf[i] - pp[i] * tr[i];
}

extern "C" void kernel_launch(void* const* d_in, const int* in_sizes, int n_in,
                              void* d_out, int out_size, void* d_ws, size_t ws_size,
                              hipStream_t stream) {
  const float* pt  = (const float*)d_in[0];
  const float* x   = (const float*)d_in[1];
  const float* pp  = (const float*)d_in[3];
  const float* gw0 = (const float*)d_in[4];
  const float* gb0 = (const float*)d_in[5];
  const float* gw1 = (const float*)d_in[6];
  const float* gb1 = (const float*)d_in[7];
  const float* gw2 = (const float*)d_in[8];
  const float* gb2 = (const float*)d_in[9];
  const float* gdw = (const float*)d_in[10];
  const float* gdb = (const float*)d_in[11];
  const float* bw0 = (const float*)d_in[12];
  const float* bb0 = (const float*)d_in[13];
  const float* bw1 = (const float*)d_in[14];
  const float* bb1 = (const float*)d_in[15];
  const float* bdw = (const float*)d_in[16];
  const float* bdb = (const float*)d_in[17];
  float* out = (float*)d_out;

  char* w = (char*)d_ws;
  size_t used = 0;
  auto alloc = [&](size_t nbytes) -> void* {
    void* r = w + used;
    used += (nbytes + 255) & ~(size_t)255;
    return r;
  };
  bf16* gw0b = (bf16*)alloc((size_t)128 * 1024 * 2);
  bf16* gw0t = (bf16*)alloc((size_t)1024 * 128 * 2);
  bf16* gw1t = (bf16*)alloc((size_t)1024 * 1024 * 2);
  bf16* gw2t = (bf16*)alloc((size_t)1024 * 1024 * 2);
  bf16* gdwt = (bf16*)alloc((size_t)128 * 1024 * 2);
  bf16* bw0t = (bf16*)alloc((size_t)512 * 192 * 2);
  bf16* bw1t = (bf16*)alloc((size_t)512 * 512 * 2);
  bf16* Xg   = (bf16*)alloc((size_t)1024 * 128 * 2);
  bf16* Xb   = (bf16*)alloc((size_t)1024 * 192 * 2);
  bf16* h0b  = (bf16*)alloc((size_t)1024 * 1024 * 2);
  bf16* h1b  = (bf16*)alloc((size_t)1024 * 1024 * 2);
  bf16* h2b  = (bf16*)alloc((size_t)1024 * 1024 * 2);
  bf16* e0b  = (bf16*)alloc((size_t)1024 * 512 * 2);
  bf16* e1b  = (bf16*)alloc((size_t)1024 * 512 * 2);
  bf16* d0b  = (bf16*)alloc((size_t)1024 * 1024 * 2);
  bf16* d1b  = (bf16*)alloc((size_t)1024 * 960 * 2);
  bf16* d2b  = (bf16*)alloc((size_t)1024 * 896 * 2);
  float* gf  = (float*)alloc(1024 * 4);
  float* tr  = (float*)alloc(1024 * 4);

  const size_t perSample = (size_t)128 * 1024 * 2;     // 256 KB of Upr rows
  size_t avail = (ws_size > used) ? ws_size - used : 0;
  int CH = (int)(avail / (2 * perSample));   // double-buffered Upr
  if (CH > 256) CH = 256;
  while (CH & (CH - 1)) CH &= CH - 1;        // pow2 -> divides 1024, equal chunks
  if (CH < 1) CH = 1;
  bf16* UprA = (bf16*)alloc((size_t)CH * perSample);
  bf16* UprB = (bf16*)alloc((size_t)CH * perSample);
  const int nCh = 1024 / CH;
  const int ch8 = (CH + 7) & ~7;

  hipMemsetAsync(tr, 0, 1024 * 4, stream);

  {
    PArgs a{gw0, gw1, gw2, gdw, bw0, bw1, pt, x,
            gw0b, gw0t, gw1t, gw2t, gdwt, bw0t, bw1t, Xg, Xb};
    kt_prep<<<dim3(1944), 256, 0, stream>>>(a);
  }

  // F1 = L0 ∪ e0
  {
    FArgs a{}; a.A = Xg; a.lda = 128; a.Bt = gw0t; a.ldb = 128; a.bias = gb0;
    a.C = h0b; a.ldc = 1024; a.D = d0b; a.ldd = 1024; a.K = 128; a.realN = 1024;
    a.gridX = 8;   // 64 blocks
    FArgs b{}; b.A = Xb; b.lda = 192; b.Bt = bw0t; b.ldb = 192; b.bias = bb0;
    b.C = e0b; b.ldc = 512; b.K = 192; b.realN = 512; b.gridX = 8;  // 32 blocks
    kt_fwd2<<<dim3(96), 256, 0, stream>>>(a, 64, b);
  }
  // F2 = L1 ∪ e1
  {
    FArgs a{}; a.A = h0b; a.lda = 1024; a.Bt = gw1t; a.ldb = 1024; a.bias = gb1;
    a.C = h1b; a.ldc = 1024; a.D = d1b; a.ldd = 960; a.K = 1024; a.realN = 960;
    a.gridX = 8;   // 64 blocks
    FArgs b{}; b.A = e0b; b.lda = 512; b.Bt = bw1t; b.ldb = 512; b.bias = bb1;
    b.C = e1b; b.ldc = 512; b.K = 512; b.realN = 448; b.gridX = 8;  // 32 blocks
    kt_fwd2<<<dim3(96), 256, 0, stream>>>(a, 64, b);
  }
  // F3 = L2 (g0 no longer exists)
  {
    FArgs a{}; a.A = h1b; a.lda = 1024; a.Bt = gw2t; a.ldb = 1024; a.bias = gb2;
    a.C = h2b; a.ldc = 1024; a.D = d2b; a.ldd = 896; a.K = 1024; a.realN = 896;
    a.gridX = 8;   // 56 blocks
    kt_fwd1<<<dim3(56), 256, 0, stream>>>(a);
  }
  // F4 = dx ∪ gdot
  {
    FArgs a{}; a.A = h2b; a.lda = 1024; a.Bt = gdwt; a.ldb = 1024; a.bias = gdb;
    a.outF = out; a.ldo = 128; a.K = 896; a.realN = 128; a.gridX = 8;  // 8 blocks
    kt_dxgdot<<<dim3(8 + 256), 256, 0, stream>>>(a, 8, e1b, bdw, bdb, gf, out + 131072);
  }

  // ---- chunk-pipelined trace: B1(c0); [B2(c)∪B1(c+1)]...; B2(last) ----
  // P0: B1(c0) -> UprA
  {
    T12 a{};
    a.A1 = gw1t; a.w0b = gw0b; a.d0b = d0b; a.d1b = d1b;
    a.UprW = UprA; a.i0b1 = 0; a.ch = CH;
    kt_b12<<<dim3(8 * ch8), 256, 0, stream>>>(a, 0, 8 * ch8);
  }
  for (int c = 0; c < nCh; ++c) {
    bf16* uprCur = (c & 1) ? UprB : UprA;
    bf16* uprNxt = (c & 1) ? UprA : UprB;
    const int nB2 = 8 * ch8;
    const int nB1 = (c + 1 < nCh) ? 8 * ch8 : 0;
    T12 a{};
    a.A2 = gw2t; a.UprR = uprCur; a.d2b = d2b; a.gdw = gdw; a.tr = tr;
    a.i0b2 = c * CH;
    a.A1 = gw1t; a.w0b = gw0b; a.d0b = d0b; a.d1b = d1b;
    a.UprW = uprNxt; a.i0b1 = (c + 1) * CH;
    a.ch = CH;
    kt_b12<<<dim3(nB2 + nB1), 256, 0, stream>>>(a, nB2, nB1);
  }

  kt_fin<<<dim3(4), 256, 0, stream>>>(gf, tr, pp, out + 132096);
}

// Round 8
// 840.437 us; speedup vs baseline: 1.0839x; 1.0839x over previous
//
#include <hip/hip_runtime.h>

// R24: revert to the session-best R16 structure (128^2 tiles, 256 thr,
// 4 blk/CU, bounce epilogue — 793us baseline), keeping ONE validated win
// from R17-R23's exploration: B1's B-operand built on the fly
// (w0 ⊙ d0, g0_body's exact float-mul->bf16-round) instead of a
// materialized G0. Validated in R21: B1 FETCH 52->10.6MB. This deletes
// the g0-compose work R16 hid in F3/B2 tails (~4x64MB writes + reads),
// G0's workspace, and the fused-tail grids. All other code paths are
// byte-identical to R16. Ledger: 8 structural variants (schedules,
// occupancy, byte-halving, XCD pinning, dispatch fusion, chunk
// pipelining) all pinned at ~90us/trace-dispatch with no saturated pipe
// -> latency plateau structural to K=1024; this round banks the safe win.
// Numerics: OTF B bitwise == g0_body's G0 rows -> Upr bitwise identical;
// tr unchanged. absmax must stay 0.009765625.

typedef __bf16 bf16;
typedef __bf16 bf16x8 __attribute__((ext_vector_type(8)));
typedef float floatx4 __attribute__((ext_vector_type(4)));

#if defined(__has_builtin)
#if __has_builtin(__builtin_amdgcn_global_load_lds)
#define HAVE_GLL 1
#endif
#endif

typedef __attribute__((address_space(3))) char lds_char_t;
typedef __attribute__((address_space(1))) const char gbl_char_t;

__device__ inline void async_load16(const void* gp, void* lp) {
#ifdef HAVE_GLL
  __builtin_amdgcn_global_load_lds((gbl_char_t*)gp, (lds_char_t*)lp, 16, 0, 0);
#else
  *(bf16x8*)lp = *(const bf16x8*)gp;
#endif
}

__device__ inline void stage_async(const bf16* src, long row0, int ld, int kc,
                                   bf16* dst, int wid, int sr8, int cph) {
#pragma unroll
  for (int t = 0; t < 4; ++t) {
    const int r = (wid * 4 + t) * 8 + sr8;
    const int csrc = (cph - r) & 7;
    async_load16(src + (row0 + r) * (size_t)ld + kc + csrc * 8,
                 dst + r * 64 + cph * 8);
  }
}

// On-the-fly B staging for B1: tile row r = gene dim d=r of one sample;
// value = w0b[wsel][k] * d0[k] with g0_body's exact formula and rounding.
__device__ inline void stage_b_otf(const bf16* w0b, const bf16* d0row, int kc,
                                   bf16* dst, int wid, int sr8, int cph) {
#pragma unroll
  for (int t = 0; t < 4; ++t) {
    const int r = (wid * 4 + t) * 8 + sr8;
    const int csrc = (cph - r) & 7;
    const int wsel = (r + 1 < 128) ? r + 1 : 127;   // d==127 pad (masked in B2)
    const int off = kc + csrc * 8;
    bf16x8 wv = *(const bf16x8*)(w0b + wsel * 1024 + off);
    bf16x8 dv = *(const bf16x8*)(d0row + off);
    bf16x8 o;
#pragma unroll
    for (int k = 0; k < 8; ++k) o[k] = (bf16)((float)wv[k] * (float)dv[k]);
    *(bf16x8*)(dst + r * 64 + cph * 8) = o;
  }
}

__device__ inline void mfma_block(const bf16* As, const bf16* Bs,
                                  floatx4 (&acc)[4][4], int wm, int wn,
                                  int l16, int quad) {
#pragma unroll
  for (int ks = 0; ks < 2; ++ks) {
    bf16x8 af[4], bfv[4];
#pragma unroll
    for (int mt = 0; mt < 4; ++mt) {
      const int r = wm * 64 + mt * 16 + l16;
      const int c = (ks * 4 + quad + r) & 7;
      af[mt] = *(const bf16x8*)(As + r * 64 + c * 8);
    }
#pragma unroll
    for (int nt = 0; nt < 4; ++nt) {
      const int r = wn * 64 + nt * 16 + l16;
      const int c = (ks * 4 + quad + r) & 7;
      bfv[nt] = *(const bf16x8*)(Bs + r * 64 + c * 8);
    }
#pragma unroll
    for (int mt = 0; mt < 4; ++mt)
#pragma unroll
      for (int nt = 0; nt < 4; ++nt)
        acc[mt][nt] = __builtin_amdgcn_mfma_f32_16x16x32_bf16(af[mt], bfv[nt], acc[mt][nt], 0, 0, 0);
  }
}

// ---------------- trace GEMMs (R16 bodies; B1 with OTF B) ----------------
struct TArgs {
  const bf16* A;     // gw1t / gw2t (ld 1024, zero-padded rows)
  const bf16* w0b;   // gw0b 128x1024 (B1 only)
  const bf16* d0b;   // 1024x1024    (B1 only)
  const bf16* d1b;   // 1024x960     (B1 scale)
  bf16* Upr;
  const bf16* d2b;   // 1024x896     (B2 scale)
  const float* gdw;  // 896x128 f32  (B2)
  float* tr;
  int i0; int ch;
};

// B1: U' rows = d1 * (gw1^T @ [w0 ⊙ d0]-rows)
__global__ __launch_bounds__(256, 4) void kt_b1(TArgs p) {
  const int idx = blockIdx.x;
  const int mt8 = (idx >> 3) & 7;
  const int nb  = ((idx >> 6) << 3) + (idx & 7);
  if (nb >= p.ch) return;

  __shared__ __align__(16) char lds[34816];
  bf16* As = (bf16*)lds;
  bf16* Bs = As + 8192;
  bf16* bounce = (bf16*)lds;

  const int tid  = threadIdx.x;
  const int wid  = tid >> 6, lane = tid & 63;
  const int wm   = wid & 1, wn = wid >> 1;
  const int quad = lane >> 4, l16 = lane & 15;
  const int sr8  = lane >> 3, cph = lane & 7;
  const int m0   = mt8 * 128;
  const int ig   = p.i0 + nb;
  const int n0   = nb * 128;
  const bf16* d0row = p.d0b + (size_t)ig * 1024;

  floatx4 acc[4][4];
#pragma unroll
  for (int a = 0; a < 4; ++a)
#pragma unroll
    for (int b = 0; b < 4; ++b)
#pragma unroll
      for (int r = 0; r < 4; ++r) acc[a][b][r] = 0.0f;

  for (int kc = 0; kc < 1024; kc += 64) {
    stage_async(p.A, m0, 1024, kc, As, wid, sr8, cph);
    stage_b_otf(p.w0b, d0row, kc, Bs, wid, sr8, cph);
    __syncthreads();
    mfma_block(As, Bs, acc, wm, wn, l16, quad);
    __syncthreads();
  }

#pragma unroll
  for (int nt = 0; nt < 4; ++nt) {
    const int nl = wn * 64 + nt * 16 + l16;
#pragma unroll
    for (int mt = 0; mt < 4; ++mt)
#pragma unroll
      for (int r = 0; r < 4; ++r) {
        const int ml = wm * 64 + mt * 16 + quad * 4 + r;
        const int mg = m0 + ml;
        const float d1v = (mg < 960) ? (float)p.d1b[(size_t)ig * 960 + mg] : 0.0f;
        bounce[nl * 136 + ml] = (bf16)(acc[mt][nt][r] * d1v);
      }
  }
  __syncthreads();
  const int r2 = tid >> 1, half16 = tid & 1;
  const int chLim = (mt8 == 7) ? 8 : 16;   // cols >=960 never read (B2 K=960)
#pragma unroll
  for (int c = 0; c < 8; ++c) {
    const int ch16 = half16 * 8 + c;
    if (ch16 < chLim) {
      bf16x8 v = *(const bf16x8*)(bounce + r2 * 136 + ch16 * 8);
      *(bf16x8*)(p.Upr + (size_t)(n0 + r2) * 1024 + m0 + ch16 * 8) = v;
    }
  }
}

// B2: tr[ig] += sum_d ((gw2t @ Upr) * d2 * gdw[:,d])
__global__ __launch_bounds__(256, 4) void kt_b2(TArgs p) {
  const int idx = blockIdx.x;
  const int mt8 = (idx >> 3) & 7;
  const int nb  = ((idx >> 6) << 3) + (idx & 7);
  if (nb >= p.ch || mt8 == 7) return;      // B2 has 7 m-tiles (M=896)

  __shared__ __align__(16) char lds[34816];
  __shared__ float red4[4];
  bf16* As = (bf16*)lds;
  bf16* Bs = As + 8192;

  const int tid  = threadIdx.x;
  const int wid  = tid >> 6, lane = tid & 63;
  const int wm   = wid & 1, wn = wid >> 1;
  const int quad = lane >> 4, l16 = lane & 15;
  const int sr8  = lane >> 3, cph = lane & 7;
  const int m0   = mt8 * 128;
  const int ig   = p.i0 + nb;
  const int n0   = nb * 128;

  floatx4 acc[4][4];
#pragma unroll
  for (int a = 0; a < 4; ++a)
#pragma unroll
    for (int b = 0; b < 4; ++b)
#pragma unroll
      for (int r = 0; r < 4; ++r) acc[a][b][r] = 0.0f;

  for (int kc = 0; kc < 960; kc += 64) {
    stage_async(p.A, m0, 1024, kc, As, wid, sr8, cph);
    stage_async(p.Upr, n0, 1024, kc, Bs, wid, sr8, cph);
    __syncthreads();
    mfma_block(As, Bs, acc, wm, wn, l16, quad);
    __syncthreads();
  }

  float s = 0.0f;
#pragma unroll
  for (int nt = 0; nt < 4; ++nt) {
    const int d = wn * 64 + nt * 16 + l16;
    if (d < 127) {
#pragma unroll
      for (int mt = 0; mt < 4; ++mt)
#pragma unroll
        for (int r = 0; r < 4; ++r) {
          const int mg = m0 + wm * 64 + mt * 16 + quad * 4 + r;  // < 896
          const float w = (float)p.d2b[(size_t)ig * 896 + mg] * p.gdw[mg * 128 + d];
          s += acc[mt][nt][r] * w;
        }
    }
  }
#pragma unroll
  for (int off = 1; off < 64; off <<= 1) s += __shfl_xor(s, off, 64);
  if (lane == 0) red4[wid] = s;
  __syncthreads();
  if (tid == 0) atomicAdd(p.tr + ig, red4[0] + red4[1] + red4[2] + red4[3]);
}

// ---------------- forward GEMMs (R16, unchanged) ----------------
struct FArgs {
  const bf16* A; int lda;
  const bf16* Bt; int ldb;
  const float* bias;
  bf16* C; int ldc;
  bf16* D; int ldd;
  float* outF; int ldo;
  int K; int realN; int gridX;
};

template <int ACT>
__device__ inline void fwd_body(const FArgs& p, int bx, bf16* As, bf16* Bs) {
  const int tid  = threadIdx.x;
  const int wid  = tid >> 6, lane = tid & 63;
  const int wm   = wid & 1, wn = wid >> 1;
  const int quad = lane >> 4, l16 = lane & 15;
  const int sr8  = lane >> 3, cph = lane & 7;
  const int m0   = (bx % p.gridX) * 128;
  const int bn0  = (bx / p.gridX) * 128;

  floatx4 acc[4][4];
#pragma unroll
  for (int a = 0; a < 4; ++a)
#pragma unroll
    for (int b = 0; b < 4; ++b)
#pragma unroll
      for (int r = 0; r < 4; ++r) acc[a][b][r] = 0.0f;

  for (int kc = 0; kc < p.K; kc += 64) {
    stage_async(p.A, m0, p.lda, kc, As, wid, sr8, cph);
    stage_async(p.Bt, bn0, p.ldb, kc, Bs, wid, sr8, cph);
    __syncthreads();
    mfma_block(As, Bs, acc, wm, wn, l16, quad);
    __syncthreads();
  }

#pragma unroll
  for (int nt = 0; nt < 4; ++nt) {
    const int ng = bn0 + wn * 64 + nt * 16 + l16;
    const float bv = (ng < p.realN) ? p.bias[ng] : 0.0f;
#pragma unroll
    for (int mt = 0; mt < 4; ++mt)
#pragma unroll
      for (int r = 0; r < 4; ++r) {
        const int i = m0 + wm * 64 + mt * 16 + quad * 4 + r;
        const float v = acc[mt][nt][r] + bv;
        if (ACT) {
          const float t = tanhf(v);
          p.C[(size_t)i * p.ldc + ng] = (ng < p.realN) ? (bf16)t : (bf16)0.0f;
          if (p.D && ng < p.realN)
            p.D[(size_t)i * p.ldd + ng] = (bf16)(1.0f - t * t);
        } else if (ng < p.realN) {
          p.outF[(size_t)i * p.ldo + ng] = v;
        }
      }
  }
}

__global__ __launch_bounds__(256) void kt_fwd2(FArgs a, int na, FArgs b) {
  __shared__ __align__(16) bf16 As[8192];
  __shared__ __align__(16) bf16 Bs[8192];
  const int bx = blockIdx.x;
  if (bx < na) fwd_body<1>(a, bx, As, Bs);
  else         fwd_body<1>(b, bx - na, As, Bs);
}

__global__ __launch_bounds__(256) void kt_fwd1(FArgs a) {
  __shared__ __align__(16) bf16 As[8192];
  __shared__ __align__(16) bf16 Bs[8192];
  fwd_body<1>(a, blockIdx.x, As, Bs);
}

__global__ __launch_bounds__(256) void kt_dxgdot(FArgs a, int na,
                                                 const bf16* e1b, const float* bdw,
                                                 const float* bdb, float* gf,
                                                 float* gout) {
  __shared__ __align__(16) bf16 As[8192];
  __shared__ __align__(16) bf16 Bs[8192];
  const int bx = blockIdx.x;
  if (bx < na) { fwd_body<0>(a, bx, As, Bs); return; }
  const int i = (bx - na) * 4 + (threadIdx.x >> 6);
  const int lane = threadIdx.x & 63;
  float s = 0.0f;
  for (int k = lane; k < 448; k += 64) s += (float)e1b[(size_t)i * 512 + k] * bdw[k];
#pragma unroll
  for (int off = 32; off > 0; off >>= 1) s += __shfl_down(s, off, 64);
  if (lane == 0) {
    const float v = s + bdb[0];
    gf[i] = v;
    gout[i] = v;
  }
}

// ---------------- fused prep with LDS-tiled transposes (R16) ----------------
struct PArgs {
  const float *gw0, *gw1, *gw2, *gdw, *bw0, *bw1, *pt, *x;
  bf16 *gw0b, *gw0t, *gw1t, *gw2t, *gdwt, *bw0t, *bw1t, *Xg, *Xb;
};

__device__ inline void tpose_tile(bf16* dst, const float* src, int R, int C,
                                  int ldd, int tile, int tilesX, float* tl,
                                  int tid) {
  const int r0 = (tile % tilesX) * 64;
  const int c0 = (tile / tilesX) * 64;
  const int tx = tid & 63, ty0 = tid >> 6;
#pragma unroll
  for (int i = 0; i < 16; ++i) {
    const int ty = ty0 + i * 4;
    const int r = r0 + ty, c = c0 + tx;
    tl[ty * 65 + tx] = (r < R && c < C) ? src[(size_t)r * C + c] : 0.0f;
  }
  __syncthreads();
#pragma unroll
  for (int i = 0; i < 16; ++i) {
    const int ty = ty0 + i * 4;
    dst[(size_t)(c0 + ty) * ldd + r0 + tx] = (bf16)tl[tx * 65 + ty];
  }
}

__global__ __launch_bounds__(256) void kt_prep(PArgs p) {
  __shared__ float tl[64 * 65];
  int b = blockIdx.x;
  const int t = threadIdx.x;
  if (b < 512) { p.gw0b[b * 256 + t] = (bf16)p.gw0[b * 256 + t]; return; }
  b -= 512;
  if (b < 768) {  // build Xg/Xb
    const int idx = b * 256 + t;
    const int i = idx / 192, c = idx % 192;
    const float s = p.pt[0];
    float vb;
    if (c == 0) vb = s;
    else if (c <= 128) vb = p.x[i * 128 + c - 1];
    else vb = 0.0f;
    p.Xb[i * 192 + c] = (bf16)vb;
    if (c < 128) p.Xg[i * 128 + c] = (bf16)((c == 0) ? s : p.x[i * 128 + c - 1]);
    return;
  }
  b -= 768;
  if (b < 32)  { tpose_tile(p.gw0t, p.gw0, 128, 1024, 128, b, 2, tl, t);  return; }
  b -= 32;
  if (b < 256) { tpose_tile(p.gw1t, p.gw1, 1024, 960, 1024, b, 16, tl, t); return; }
  b -= 256;
  if (b < 256) { tpose_tile(p.gw2t, p.gw2, 960, 896, 1024, b, 16, tl, t); return; }
  b -= 256;
  if (b < 32)  { tpose_tile(p.gdwt, p.gdw, 896, 128, 1024, b, 16, tl, t); return; }
  b -= 32;
  if (b < 24)  { tpose_tile(p.bw0t, p.bw0, 129, 512, 192, b, 3, tl, t);  return; }
  b -= 24;
  if (b < 64)  { tpose_tile(p.bw1t, p.bw1, 512, 448, 512, b, 8, tl, t);  return; }
}

__global__ __launch_bounds__(256) void kt_fin(const float* gf, const float* tr,
                                              const float* pp, float* dp) {
  const int i = blockIdx.x * 256 + threadIdx.x;
  if (i < 1024) dp[i] = gf[i] - pp[i] * tr[i];
}

extern "C" void kernel_launch(void* const* d_in, const int* in_sizes, int n_in,
                              void* d_out, int out_size, void* d_ws, size_t ws_size,
                              hipStream_t stream) {
  const float* pt  = (const float*)d_in[0];
  const float* x   = (const float*)d_in[1];
  const float* pp  = (const float*)d_in[3];
  const float* gw0 = (const float*)d_in[4];
  const float* gb0 = (const float*)d_in[5];
  const float* gw1 = (const float*)d_in[6];
  const float* gb1 = (const float*)d_in[7];
  const float* gw2 = (const float*)d_in[8];
  const float* gb2 = (const float*)d_in[9];
  const float* gdw = (const float*)d_in[10];
  const float* gdb = (const float*)d_in[11];
  const float* bw0 = (const float*)d_in[12];
  const float* bb0 = (const float*)d_in[13];
  const float* bw1 = (const float*)d_in[14];
  const float* bb1 = (const float*)d_in[15];
  const float* bdw = (const float*)d_in[16];
  const float* bdb = (const float*)d_in[17];
  float* out = (float*)d_out;

  char* w = (char*)d_ws;
  size_t used = 0;
  auto alloc = [&](size_t nbytes) -> void* {
    void* r = w + used;
    used += (nbytes + 255) & ~(size_t)255;
    return r;
  };
  bf16* gw0b = (bf16*)alloc((size_t)128 * 1024 * 2);
  bf16* gw0t = (bf16*)alloc((size_t)1024 * 128 * 2);
  bf16* gw1t = (bf16*)alloc((size_t)1024 * 1024 * 2);
  bf16* gw2t = (bf16*)alloc((size_t)1024 * 1024 * 2);
  bf16* gdwt = (bf16*)alloc((size_t)128 * 1024 * 2);
  bf16* bw0t = (bf16*)alloc((size_t)512 * 192 * 2);
  bf16* bw1t = (bf16*)alloc((size_t)512 * 512 * 2);
  bf16* Xg   = (bf16*)alloc((size_t)1024 * 128 * 2);
  bf16* Xb   = (bf16*)alloc((size_t)1024 * 192 * 2);
  bf16* h0b  = (bf16*)alloc((size_t)1024 * 1024 * 2);
  bf16* h1b  = (bf16*)alloc((size_t)1024 * 1024 * 2);
  bf16* h2b  = (bf16*)alloc((size_t)1024 * 1024 * 2);
  bf16* e0b  = (bf16*)alloc((size_t)1024 * 512 * 2);
  bf16* e1b  = (bf16*)alloc((size_t)1024 * 512 * 2);
  bf16* d0b  = (bf16*)alloc((size_t)1024 * 1024 * 2);
  bf16* d1b  = (bf16*)alloc((size_t)1024 * 960 * 2);
  bf16* d2b  = (bf16*)alloc((size_t)1024 * 896 * 2);
  float* gf  = (float*)alloc(1024 * 4);
  float* tr  = (float*)alloc(1024 * 4);

  const size_t perSample = (size_t)128 * 1024 * 2;     // 256 KB of Upr rows
  size_t avail = (ws_size > used) ? ws_size - used : 0;
  int CH = (int)(avail / perSample);
  if (CH > 256) CH = 256;   // 4 chunks
  if (CH < 1) CH = 1;
  bf16* Upr = (bf16*)(w + used);

  hipMemsetAsync(tr, 0, 1024 * 4, stream);

  {
    PArgs a{gw0, gw1, gw2, gdw, bw0, bw1, pt, x,
            gw0b, gw0t, gw1t, gw2t, gdwt, bw0t, bw1t, Xg, Xb};
    kt_prep<<<dim3(1944), 256, 0, stream>>>(a);
  }

  // F1 = L0 ∪ e0
  {
    FArgs a{}; a.A = Xg; a.lda = 128; a.Bt = gw0t; a.ldb = 128; a.bias = gb0;
    a.C = h0b; a.ldc = 1024; a.D = d0b; a.ldd = 1024; a.K = 128; a.realN = 1024;
    a.gridX = 8;   // 64 blocks
    FArgs b{}; b.A = Xb; b.lda = 192; b.Bt = bw0t; b.ldb = 192; b.bias = bb0;
    b.C = e0b; b.ldc = 512; b.K = 192; b.realN = 512; b.gridX = 8;  // 32 blocks
    kt_fwd2<<<dim3(96), 256, 0, stream>>>(a, 64, b);
  }
  // F2 = L1 ∪ e1
  {
    FArgs a{}; a.A = h0b; a.lda = 1024; a.Bt = gw1t; a.ldb = 1024; a.bias = gb1;
    a.C = h1b; a.ldc = 1024; a.D = d1b; a.ldd = 960; a.K = 1024; a.realN = 960;
    a.gridX = 8;   // 64 blocks
    FArgs b{}; b.A = e0b; b.lda = 512; b.Bt = bw1t; b.ldb = 512; b.bias = bb1;
    b.C = e1b; b.ldc = 512; b.K = 512; b.realN = 448; b.gridX = 8;  // 32 blocks
    kt_fwd2<<<dim3(96), 256, 0, stream>>>(a, 64, b);
  }
  // F3 = L2 (g0 tail gone — G0 no longer exists)
  {
    FArgs a{}; a.A = h1b; a.lda = 1024; a.Bt = gw2t; a.ldb = 1024; a.bias = gb2;
    a.C = h2b; a.ldc = 1024; a.D = d2b; a.ldd = 896; a.K = 1024; a.realN = 896;
    a.gridX = 8;   // 56 blocks
    kt_fwd1<<<dim3(56), 256, 0, stream>>>(a);
  }
  // F4 = dx ∪ gdot
  {
    FArgs a{}; a.A = h2b; a.lda = 1024; a.Bt = gdwt; a.ldb = 1024; a.bias = gdb;
    a.outF = out; a.ldo = 128; a.K = 896; a.realN = 128; a.gridX = 8;  // 8 blocks
    kt_dxgdot<<<dim3(8 + 256), 256, 0, stream>>>(a, 8, e1b, bdw, bdb, gf, out + 131072);
  }

  for (int i0 = 0; i0 < 1024; i0 += CH) {
    const int ch  = (1024 - i0 < CH) ? (1024 - i0) : CH;
    const int ch8 = (ch + 7) & ~7;
    {  // B1: U' = D1 * (gw1^T @ [w0 ⊙ d0]), M pad 1024, K=1024
      TArgs a{}; a.A = gw1t; a.w0b = gw0b; a.d0b = d0b; a.d1b = d1b;
      a.Upr = Upr; a.i0 = i0; a.ch = ch;
      kt_b1<<<dim3(8 * ch8), 256, 0, stream>>>(a);
    }
    {  // B2: trace reduce, K=960
      TArgs a{}; a.A = gw2t; a.Upr = Upr; a.d2b = d2b; a.gdw = gdw; a.tr = tr;
      a.i0 = i0; a.ch = ch;
      kt_b2<<<dim3(8 * ch8), 256, 0, stream>>>(a);
    }
  }

  kt_fin<<<dim3(4), 256, 0, stream>>>(gf, tr, pp, out + 132096);
}